// Round 5
// baseline (713.726 us; speedup 1.0000x reference)
//
#include <hip/hip_runtime.h>
#include <hip/hip_bf16.h>
#include <stdint.h>

typedef __bf16 bf16_t;
typedef __bf16 bf16x8 __attribute__((ext_vector_type(8)));
typedef __bf16 bf16x4 __attribute__((ext_vector_type(4)));
typedef float  v16f   __attribute__((ext_vector_type(16)));

#define GLDS16(gp, lp)                                                         \
  __builtin_amdgcn_global_load_lds(                                            \
      (__attribute__((address_space(1))) void*)(gp),                           \
      (__attribute__((address_space(3))) void*)(lp), 16, 0, 0)

#define BATCH 2048
#define KEXP  64
#define NOUT  512
#define R1    1024

// ---------------------------------------------------------------- cast u -> bf16
__global__ __launch_bounds__(256) void cast_u_k(const float* __restrict__ u,
                                                bf16_t* __restrict__ ub) {
  int idx = blockIdx.x * 256 + threadIdx.x;          // float4 index
  float4 v = ((const float4*)u)[idx];
  bf16x4 o;
  o.x = (bf16_t)v.x; o.y = (bf16_t)v.y; o.z = (bf16_t)v.z; o.w = (bf16_t)v.w;
  ((bf16x4*)ub)[idx] = o;
}

// ------------------------------------------- cast W_con|W_recon -> combined bf16
// wb layout: [k][n(0..1023)][i], n<512 from W_con, n>=512 from W_recon.
// R5: reverted to plain coalesced 1-float4/thread (R4's NT+grid-stride was +17us).
__global__ __launch_bounds__(256) void cast_w_k(const float* __restrict__ wcon,
                                                const float* __restrict__ wrec,
                                                bf16_t* __restrict__ wb) {
  size_t idx = (size_t)blockIdx.x * 256 + threadIdx.x;  // float4 index
  size_t e = idx << 2;
  int k = (int)(e >> 20);
  int n = (int)((e >> 10) & 1023);
  int i = (int)(e & 1023);
  const float* src = (n < NOUT)
      ? (wcon + (((size_t)k * NOUT + n) << 10) + i)
      : (wrec + (((size_t)k * NOUT + (n - NOUT)) << 10) + i);
  float4 v = *(const float4*)src;
  bf16x4 o;
  o.x = (bf16_t)v.x; o.y = (bf16_t)v.y; o.z = (bf16_t)v.z; o.w = (bf16_t)v.w;
  ((bf16x4*)wb)[idx] = o;
}

// ------------------------------------------------------------- d2 (fp32 GEMM)
// d2[b,k] = || S_k^T (mu_k - z_b) ||^2.  Block = (k, 64-batch tile).
// dv staged in LDS; S_k staged in 16-row chunks, non-redundant coalesced loads.
__global__ __launch_bounds__(256) void psi_d2_k(const float* __restrict__ z,
                                                const float* __restrict__ mu,
                                                const float* __restrict__ sig,
                                                float* __restrict__ d2g) {
  __shared__ float dv[64][132];   // +4 pad
  __shared__ float Ss[16][128];   // one 16-row chunk of S_k
  const int t = threadIdx.x;
  const int k = blockIdx.x;
  const int b0 = blockIdx.y * 64;

  const float* muk = mu + k * 128;
#pragma unroll
  for (int i = 0; i < 8; ++i) {
    int f4 = i * 256 + t;                 // float4 index within 64x128 tile
    int row = f4 >> 5, c4 = f4 & 31;
    float4 zq = ((const float4*)(z + (size_t)(b0 + row) * 128))[c4];
    float4 mq = ((const float4*)muk)[c4];
    float4 dq;
    dq.x = mq.x - zq.x; dq.y = mq.y - zq.y;
    dq.z = mq.z - zq.z; dq.w = mq.w - zq.w;
    *(float4*)&dv[row][c4 * 4] = dq;
  }

  const int et = t & 15, bt = t >> 4;     // e-thread, b-thread
  const float* Sk = sig + ((size_t)k << 14);
  float acc[4][8];
#pragma unroll
  for (int j = 0; j < 4; ++j)
#pragma unroll
    for (int i = 0; i < 8; ++i) acc[j][i] = 0.f;

  for (int dblk = 0; dblk < 8; ++dblk) {
    __syncthreads();                      // Ss safe to overwrite (also covers dv)
#pragma unroll
    for (int i = 0; i < 2; ++i) {
      int f4 = i * 256 + t;               // 0..511 within 16x128 chunk
      int row = f4 >> 5, c4 = f4 & 31;
      *(float4*)&Ss[row][c4 * 4] =
          ((const float4*)(Sk + (size_t)(dblk * 16 + row) * 128))[c4];
    }
    __syncthreads();

#pragma unroll
    for (int d4 = 0; d4 < 4; ++d4) {
      float4 a[4];
#pragma unroll
      for (int j = 0; j < 4; ++j)
        a[j] = *(const float4*)&dv[bt * 4 + j][dblk * 16 + d4 * 4];
#pragma unroll
      for (int dd = 0; dd < 4; ++dd) {
        float4 s0 = *(const float4*)&Ss[d4 * 4 + dd][et * 8];
        float4 s1 = *(const float4*)&Ss[d4 * 4 + dd][et * 8 + 4];
        float av[4] = {a[0][dd], a[1][dd], a[2][dd], a[3][dd]};
#pragma unroll
        for (int j = 0; j < 4; ++j) {
          acc[j][0] = fmaf(s0.x, av[j], acc[j][0]);
          acc[j][1] = fmaf(s0.y, av[j], acc[j][1]);
          acc[j][2] = fmaf(s0.z, av[j], acc[j][2]);
          acc[j][3] = fmaf(s0.w, av[j], acc[j][3]);
          acc[j][4] = fmaf(s1.x, av[j], acc[j][4]);
          acc[j][5] = fmaf(s1.y, av[j], acc[j][5]);
          acc[j][6] = fmaf(s1.z, av[j], acc[j][6]);
          acc[j][7] = fmaf(s1.w, av[j], acc[j][7]);
        }
      }
    }
  }

  float v2[4];
#pragma unroll
  for (int j = 0; j < 4; ++j) {
    float s = 0.f;
#pragma unroll
    for (int i = 0; i < 8; ++i) s = fmaf(acc[j][i], acc[j][i], s);
    v2[j] = s;
  }
#pragma unroll
  for (int j = 0; j < 4; ++j) {
    v2[j] += __shfl_xor(v2[j], 1);
    v2[j] += __shfl_xor(v2[j], 2);
    v2[j] += __shfl_xor(v2[j], 4);
    v2[j] += __shfl_xor(v2[j], 8);
  }
  if (et == 0) {
#pragma unroll
    for (int j = 0; j < 4; ++j)
      d2g[(size_t)(b0 + bt * 4 + j) * 64 + k] = v2[j];
  }
}

// ----------------------------------------------------------- softmax over k
__global__ __launch_bounds__(256) void psi_sm_k(const float* __restrict__ d2g,
                                                float* __restrict__ psi) {
  const int b = blockIdx.x * 4 + (threadIdx.x >> 6);
  const int lane = threadIdx.x & 63;
  float x = fmaxf(d2g[(size_t)b * 64 + lane], 0.0f);  // MIN_CLAMP
  float m = x;
  m = fminf(m, __shfl_xor(m, 1));  m = fminf(m, __shfl_xor(m, 2));
  m = fminf(m, __shfl_xor(m, 4));  m = fminf(m, __shfl_xor(m, 8));
  m = fminf(m, __shfl_xor(m, 16)); m = fminf(m, __shfl_xor(m, 32));
  float ex = __expf(m - x);
  float s = ex;
  s += __shfl_xor(s, 1);  s += __shfl_xor(s, 2);  s += __shfl_xor(s, 4);
  s += __shfl_xor(s, 8);  s += __shfl_xor(s, 16); s += __shfl_xor(s, 32);
  psi[(size_t)b * 64 + lane] = ex / s;
}

// ------------------------------------------------------- fused bf16 MFMA GEMM
// R5: 32x32x16 MFMA (pipe ceiling 2382 vs 2075 TF). Per wave: 64x64 quadrant
// as 2x2 MFMAs. Swizzle preserved: phys chunk = (ks*2+(lane>>5)) ^ (row&7);
// each 8-lane phase covers 8 consecutive rows -> 8 distinct chunks -> 0 conf.
// C/D layout (m74/m101): col=lane&31, row=(reg&3)+8*(reg>>2)+4*(lane>>5).
// wlds hoisted: all 8 experts' weights loaded once per block.
__global__ __launch_bounds__(256, 2)
void fused_gemm(const bf16_t* __restrict__ ub,   // [2048][1024]
                const bf16_t* __restrict__ wb,   // [64][1024][1024]
                const float* __restrict__ psi,   // [2048][64]
                const float* __restrict__ member,// [2048][64]
                float* __restrict__ out) {       // y[2048*512] ++ x[2048*512]
  __shared__ bf16_t Alds[128 * 64];
  __shared__ bf16_t Blds[128 * 64];
  __shared__ float wlds[8 * 128];                // [expert][row]

  const int t = threadIdx.x, lane = t & 63, wv = t >> 6;
  const int bm0 = blockIdx.x * 128;
  const int n0  = blockIdx.y * 128;
  const int e0  = blockIdx.z * 8;
  const bool is_y = (n0 < NOUT);
  const float* wsel = is_y ? psi : member;
  const int wm = wv & 1, wn = wv >> 1;
  const int l31 = lane & 31, half = lane >> 5, l7 = lane & 7;

  // load all 8 experts' mixing weights once: wlds[e][row]
#pragma unroll
  for (int i = 0; i < 4; ++i) {
    int f = i * 256 + t;                 // e = f>>7, row = f&127
    wlds[f] = wsel[(size_t)(bm0 + (f & 127)) * 64 + (e0 + (f >> 7))];
  }

  v16f acc[2][2], oacc[2][2];
#pragma unroll
  for (int mi = 0; mi < 2; ++mi)
#pragma unroll
    for (int ni = 0; ni < 2; ++ni)
#pragma unroll
      for (int r = 0; r < 16; ++r) { acc[mi][ni][r] = 0.f; oacc[mi][ni][r] = 0.f; }

  const int rA = wv * 8 + (lane >> 3);             // staging row in 32-row group
  const int c8 = (((lane & 7) ^ (lane >> 3)) * 8); // swizzled source column
  const bf16_t* au  = ub + (size_t)(bm0 + rA) * R1 + c8;
  const bf16_t* bw0 = wb + (size_t)(n0 + rA) * R1 + c8;

  // precomputed row index within a 32-row block for each acc register
  int row32[16];
#pragma unroll
  for (int r = 0; r < 16; ++r) row32[r] = (r & 3) + 8 * (r >> 2) + 4 * half;

  const bf16_t* Ab = &Alds[(wm * 64 + l31) * 64];
  const bf16_t* Bb = &Blds[(wn * 64 + l31) * 64];

  for (int ke = 0; ke < 8; ++ke) {
    const bf16_t* bw = bw0 + ((size_t)(e0 + ke) << 20);
    for (int kk = 0; kk < R1; kk += 64) {
      __syncthreads();  // LDS safe to overwrite (also covers wlds on 1st pass)
#pragma unroll
      for (int j = 0; j < 4; ++j) {
        GLDS16(au + (size_t)(j * 32) * R1 + kk, &Alds[(j * 32 + wv * 8) * 64]);
        GLDS16(bw + (size_t)(j * 32) * R1 + kk, &Blds[(j * 32 + wv * 8) * 64]);
      }
      __syncthreads();  // staging complete (vmcnt drained by barrier)

#pragma unroll
      for (int ks = 0; ks < 4; ++ks) {
        const int co = (((ks * 2 + half) ^ l7)) * 8;  // swizzled chunk offset
        bf16x8 af[2], bfr[2];
#pragma unroll
        for (int i = 0; i < 2; ++i) {
          af[i]  = *(const bf16x8*)(Ab + i * 32 * 64 + co);
          bfr[i] = *(const bf16x8*)(Bb + i * 32 * 64 + co);
        }
#pragma unroll
        for (int mi = 0; mi < 2; ++mi)
#pragma unroll
          for (int ni = 0; ni < 2; ++ni)
            acc[mi][ni] = __builtin_amdgcn_mfma_f32_32x32x16_bf16(
                af[mi], bfr[ni], acc[mi][ni], 0, 0, 0);
      }
    }
    // per-expert epilogue: oacc += |acc| * w[b, ex]; reset acc
#pragma unroll
    for (int mi = 0; mi < 2; ++mi) {
      float wr[16];
#pragma unroll
      for (int r = 0; r < 16; ++r)
        wr[r] = wlds[ke * 128 + wm * 64 + mi * 32 + row32[r]];
#pragma unroll
      for (int ni = 0; ni < 2; ++ni)
#pragma unroll
        for (int r = 0; r < 16; ++r) {
          oacc[mi][ni][r] += fabsf(acc[mi][ni][r]) * wr[r];
          acc[mi][ni][r] = 0.f;
        }
    }
  }

  float* obase = is_y ? out : out + (size_t)BATCH * NOUT;
  const int oc0 = (is_y ? n0 : n0 - NOUT) + wn * 64 + l31;
#pragma unroll
  for (int mi = 0; mi < 2; ++mi)
#pragma unroll
    for (int ni = 0; ni < 2; ++ni)
#pragma unroll
      for (int r = 0; r < 16; ++r) {
        int brow = bm0 + wm * 64 + mi * 32 + row32[r];
        atomicAdd(&obase[(size_t)brow * NOUT + oc0 + ni * 32], oacc[mi][ni][r]);
      }
}

extern "C" void kernel_launch(void* const* d_in, const int* in_sizes, int n_in,
                              void* d_out, int out_size, void* d_ws, size_t ws_size,
                              hipStream_t stream) {
  const float* z    = (const float*)d_in[0];
  const float* u    = (const float*)d_in[1];
  const float* mem  = (const float*)d_in[2];
  const float* mu   = (const float*)d_in[3];
  const float* sig  = (const float*)d_in[4];
  const float* wcon = (const float*)d_in[5];
  const float* wrec = (const float*)d_in[6];
  float* out = (float*)d_out;

  char* ws = (char*)d_ws;
  bf16_t* ub  = (bf16_t*)ws;                              // 4 MiB
  bf16_t* wb  = (bf16_t*)(ws + ((size_t)4 << 20));        // 128 MiB
  float*  psw = (float*)(ws + ((size_t)132 << 20));       // 512 KiB
  float*  d2g = (float*)(ws + ((size_t)132 << 20) + ((size_t)512 << 10));

  hipMemsetAsync(d_out, 0, (size_t)out_size * sizeof(float), stream);
  cast_u_k<<<2048, 256, 0, stream>>>(u, ub);
  cast_w_k<<<65536, 256, 0, stream>>>(wcon, wrec, wb);
  psi_d2_k<<<dim3(64, 32), 256, 0, stream>>>(z, mu, sig, d2g);
  psi_sm_k<<<512, 256, 0, stream>>>(d2g, psw);
  fused_gemm<<<dim3(16, 8, 8), 256, 0, stream>>>(ub, wb, psw, mem, out);
}